// Round 2
// baseline (810.314 us; speedup 1.0000x reference)
//
#include <hip/hip_runtime.h>
#include <hip/hip_bf16.h>

// Problem constants (T, B, H, D_MODEL) = (4096, 16, 256, 256)
#define T_LEN 4096
#define BATCH 16
#define NH    256
#define DM    256
#define M_TOT (T_LEN * BATCH)   // 65536 rows for both GEMMs

typedef __hip_bfloat16 bf16;

// load/store helpers (f32 accumulate everywhere)
__device__ inline float ldf(const float* p, size_t i) { return p[i]; }
__device__ inline float ldf(const bf16* p, size_t i)  { return __bfloat162float(p[i]); }
__device__ inline void stf(float* p, size_t i, float v) { p[i] = v; }
__device__ inline void stf(bf16* p, size_t i, float v)  { p[i] = __float2bfloat16(v); }

// ---------------------------------------------------------------------------
// Prep 1: Lambda (complex decay) and gamma per head. (f32 inputs)
// Lam = exp(-exp(nu_log) + i*exp(theta_log)); gamma = sqrt(max(1-|Lam|^2,1e-8))
// ---------------------------------------------------------------------------
__global__ __launch_bounds__(256) void prep_lam_kernel(
    const float* __restrict__ nu_log, const float* __restrict__ theta_log,
    float* __restrict__ lam /* [2*NH]: re then im */, float* __restrict__ gam)
{
    int h = threadIdx.x;
    float nu  = nu_log[h];
    float th  = theta_log[h];
    float mod = expf(-expf(nu));          // |Lam| <= exp(-1) = 0.368
    float ang = expf(th);
    lam[h]      = mod * cosf(ang);
    lam[NH + h] = mod * sinf(ang);
    gam[h] = sqrtf(fmaxf(1.0f - mod * mod, 1e-8f));
}

// ---------------------------------------------------------------------------
// Prep 2: packed weight matrices (f32).
// Wa: (DM x 512) row-major. Wa[d][h]      = B_re[h][d]*gamma[h]
//                           Wa[d][256+h]  = B_im[h][d]*gamma[h]
// Wc: (512 x DM) row-major. Wc[h][d]      = C_re[d][h]
//                           Wc[256+h][d]  = -C_im[d][h]
// ---------------------------------------------------------------------------
__global__ __launch_bounds__(256) void prep_w_kernel(
    const float* __restrict__ B_re, const float* __restrict__ B_im,
    const float* __restrict__ C_re, const float* __restrict__ C_im,
    const float* __restrict__ gam,
    float* __restrict__ Wa, float* __restrict__ Wc)
{
    int idx = blockIdx.x * 256 + threadIdx.x;   // grid covers 2*131072
    if (idx < DM * 512) {
        int d = idx >> 9;
        int n = idx & 511;
        float v;
        if (n < NH) v = B_re[n * DM + d] * gam[n];
        else { int hh = n - NH; v = B_im[hh * DM + d] * gam[hh]; }
        Wa[idx] = v;
    } else {
        int j = idx - DM * 512;
        int k = j >> 8;     // 0..511
        int d = j & 255;
        float v = (k < NH) ? C_re[d * NH + k] : -C_im[d * NH + (k - NH)];
        Wc[j] = v;
    }
}

// ---------------------------------------------------------------------------
// Tiled SIMT GEMM (correctness baseline; MFMA next round).
// C[m][n] = sum_k A[m][k]*W[k][n]  (+ optional skip: D[n]*X[m][n])
// 64x64 tile per 256-thread block, 4x4 per thread, BK=16 slabs via LDS.
// Templated on element types so Bu/H can be bf16 while x/out stay f32.
// ---------------------------------------------------------------------------
#define BM 64
#define BN 64
#define BK 16

template <typename TA, typename TW, typename TC, bool SKIP>
__global__ __launch_bounds__(256) void gemm_kernel(
    const TA* __restrict__ A,   // (M,K) row-major
    const TW* __restrict__ W,   // (K,N) row-major
    TC* __restrict__ C,         // (M,N) row-major
    int M, int K, int N,
    const float* __restrict__ skip_x,  // (M,N) when SKIP
    const float* __restrict__ Dvec)    // (N,)  when SKIP
{
    __shared__ float sA[BK][BM];   // stored transposed: sA[k][m]
    __shared__ float sW[BK][BN];

    int tid = threadIdx.y * 16 + threadIdx.x;
    int m0 = blockIdx.y * BM;
    int n0 = blockIdx.x * BN;

    float acc[4][4] = {};

    for (int k0 = 0; k0 < K; k0 += BK) {
        // A slab: BM x BK
        #pragma unroll
        for (int i = tid; i < BM * BK; i += 256) {
            int r = i >> 4;   // m within tile
            int c = i & 15;   // k within slab
            sA[c][r] = ldf(A, (size_t)(m0 + r) * K + k0 + c);
        }
        // W slab: BK x BN
        #pragma unroll
        for (int i = tid; i < BK * BN; i += 256) {
            int r = i >> 6;   // k within slab
            int c = i & 63;   // n within tile
            sW[r][c] = ldf(W, (size_t)(k0 + r) * N + n0 + c);
        }
        __syncthreads();
        #pragma unroll
        for (int kk = 0; kk < BK; ++kk) {
            float a[4], w[4];
            #pragma unroll
            for (int i = 0; i < 4; ++i) a[i] = sA[kk][threadIdx.y * 4 + i];
            #pragma unroll
            for (int j = 0; j < 4; ++j) w[j] = sW[kk][threadIdx.x * 4 + j];
            #pragma unroll
            for (int i = 0; i < 4; ++i)
                #pragma unroll
                for (int j = 0; j < 4; ++j)
                    acc[i][j] += a[i] * w[j];
        }
        __syncthreads();
    }

    #pragma unroll
    for (int i = 0; i < 4; ++i) {
        int m = m0 + threadIdx.y * 4 + i;
        #pragma unroll
        for (int j = 0; j < 4; ++j) {
            int n = n0 + threadIdx.x * 4 + j;
            float v = acc[i][j];
            if (SKIP) {
                v += Dvec[n] * skip_x[(size_t)m * N + n];
            }
            stf(C, (size_t)m * N + n, v);
        }
    }
}

// ---------------------------------------------------------------------------
// Chunked scan. |Lam| <= e^-1, so a KHALO=64 warm-up from zero reproduces the
// exact recurrence to ~1e-28 relative. Chunk 0 is seeded from `state`.
// Layout of Bu/H (bf16): row m = t*BATCH + b, 512 cols = [re | im].
// One block = one (b, chunk): 256 threads = 256 heads; per-t accesses are
// 512B contiguous per block half (coalesced).
// ---------------------------------------------------------------------------
#define SCHUNK 256
#define KHALO  64

__global__ __launch_bounds__(256) void scan_kernel(
    const bf16* __restrict__ Bu, const float* __restrict__ lam,
    const int* __restrict__ starts,
    const float* __restrict__ state_re, const float* __restrict__ state_im,
    bf16* __restrict__ H)
{
    int h = threadIdx.x;
    int b = blockIdx.x & (BATCH - 1);
    int c = blockIdx.x / BATCH;

    float lr = lam[h];
    float li = lam[NH + h];

    int t0 = c * SCHUNK;
    int tstart = t0 - KHALO;
    float hre, him;
    if (tstart <= 0) {
        tstart = 0;
        hre = state_re[b * NH + h];
        him = state_im[b * NH + h];
    } else {
        hre = 0.0f; him = 0.0f;
    }
    int tend = t0 + SCHUNK;

    for (int t = tstart; t < tend; ++t) {
        size_t m = (size_t)t * BATCH + b;
        float br = __bfloat162float(Bu[m * 512 + h]);
        float bi = __bfloat162float(Bu[m * 512 + 256 + h]);
        bool st = (starts[t * BATCH + b] != 0);
        float nr = st ? br : (lr * hre - li * him + br);
        float ni = st ? bi : (lr * him + li * hre + bi);
        hre = nr; him = ni;
        if (t >= t0) {
            H[m * 512 + h]       = __float2bfloat16(hre);
            H[m * 512 + 256 + h] = __float2bfloat16(him);
        }
    }
}

// ---------------------------------------------------------------------------
// Launch. Input dict order: x, starts, state_re, state_im, nu_log, theta_log,
// B_re, B_im, C_re, C_im, D. Reference dtypes: all float32 except starts
// (bool -> const int* per harness integer rule). Output float32.
// Workspace: lam/gamma (<4KB) | Wa 512KB | Wc 512KB | Bu 64MB | H 64MB (~130MB).
// ---------------------------------------------------------------------------
extern "C" void kernel_launch(void* const* d_in, const int* in_sizes, int n_in,
                              void* d_out, int out_size, void* d_ws, size_t ws_size,
                              hipStream_t stream)
{
    const float* x         = (const float*)d_in[0];
    const int*   starts    = (const int*)d_in[1];
    const float* state_re  = (const float*)d_in[2];
    const float* state_im  = (const float*)d_in[3];
    const float* nu_log    = (const float*)d_in[4];
    const float* theta_log = (const float*)d_in[5];
    const float* B_re      = (const float*)d_in[6];
    const float* B_im      = (const float*)d_in[7];
    const float* C_re      = (const float*)d_in[8];
    const float* C_im      = (const float*)d_in[9];
    const float* Dvec      = (const float*)d_in[10];
    float* out = (float*)d_out;

    char* ws = (char*)d_ws;
    float* lam = (float*)ws;                                   // 2*NH floats
    float* gam = (float*)(ws + 2 * NH * sizeof(float));
    float* Wa = (float*)(ws + 4096);                           // DM x 512 f32 (512KB)
    float* Wc = (float*)(ws + 4096 + (size_t)DM * 512 * 4);    // 512 x DM f32 (512KB)
    bf16*  Bu = (bf16*)(ws + (2 << 20));                       // M_TOT x 512 bf16 (64MB)
    bf16*  H  = (bf16*)(ws + (2 << 20) + (size_t)M_TOT * 512 * 2); // 64MB

    prep_lam_kernel<<<1, 256, 0, stream>>>(nu_log, theta_log, lam, gam);
    prep_w_kernel<<<1024, 256, 0, stream>>>(B_re, B_im, C_re, C_im, gam, Wa, Wc);

    // Stage A: Bu = x @ Wa   (M=65536, K=256, N=512), f32 x f32 -> bf16
    gemm_kernel<float, float, bf16, false>
        <<<dim3(512 / BN, M_TOT / BM), dim3(16, 16), 0, stream>>>(
        x, Wa, Bu, M_TOT, DM, 512, nullptr, nullptr);

    // Scan: chunked, halo=64
    scan_kernel<<<(T_LEN / SCHUNK) * BATCH, 256, 0, stream>>>(
        Bu, lam, starts, state_re, state_im, H);

    // Stage C: out = H @ Wc + D*x   (M=65536, K=512, N=256), bf16 x f32 -> f32
    gemm_kernel<bf16, float, float, true>
        <<<dim3(DM / BN, M_TOT / BM), dim3(16, 16), 0, stream>>>(
        H, Wc, out, M_TOT, 512, DM, x, Dvec);
}

// Round 3
// 263.573 us; speedup vs baseline: 3.0743x; 3.0743x over previous
//
#include <hip/hip_runtime.h>
#include <hip/hip_bf16.h>

// Problem constants (T, B, H, D_MODEL) = (4096, 16, 256, 256)
#define T_LEN 4096
#define BATCH 16
#define NH    256
#define DM    256
#define M_TOT (T_LEN * BATCH)   // 65536 rows for both GEMMs

typedef __hip_bfloat16 bf16;
typedef __attribute__((ext_vector_type(8))) short bf16x8;  // 8 bf16 = 4 VGPRs
typedef __attribute__((ext_vector_type(4))) float f32x4;

// manual RTNE f32->bf16 (bit-level, matches HW RTNE for normals)
__device__ __forceinline__ unsigned short f2bf_bits(float f) {
    unsigned int u = __float_as_uint(f);
    return (unsigned short)((u + 0x7fffu + ((u >> 16) & 1u)) >> 16);
}

// ---------------------------------------------------------------------------
// Prep 1: Lambda (complex decay) and gamma per head.
// ---------------------------------------------------------------------------
__global__ __launch_bounds__(256) void prep_lam_kernel(
    const float* __restrict__ nu_log, const float* __restrict__ theta_log,
    float* __restrict__ lam /* [2*NH]: re then im */, float* __restrict__ gam)
{
    int h = threadIdx.x;
    float nu  = nu_log[h];
    float th  = theta_log[h];
    float mod = expf(-expf(nu));          // |Lam| <= exp(-1) = 0.368
    float ang = expf(th);
    lam[h]      = mod * cosf(ang);
    lam[NH + h] = mod * sinf(ang);
    gam[h] = sqrtf(fmaxf(1.0f - mod * mod, 1e-8f));
}

// ---------------------------------------------------------------------------
// Prep 2: packed transposed weights (bf16), complex-interleaved layout.
// WaT: (512 x 256) [n][k].  n=2h:   B_re[h][k]*gam[h]
//                           n=2h+1: B_im[h][k]*gam[h]
// WcT: (256 x 512) [d][k].  k=2h:   C_re[d][h]
//                           k=2h+1: -C_im[d][h]
// Both are "BT" (N x K) operands for the MFMA GEMM.
// ---------------------------------------------------------------------------
__global__ __launch_bounds__(256) void prep_w_kernel(
    const float* __restrict__ B_re, const float* __restrict__ B_im,
    const float* __restrict__ C_re, const float* __restrict__ C_im,
    const float* __restrict__ gam,
    bf16* __restrict__ WaT, bf16* __restrict__ WcT)
{
    int idx = blockIdx.x * 256 + threadIdx.x;   // covers 2 * 131072
    if (idx < 512 * 256) {
        int n = idx >> 8, k = idx & 255;
        int h = n >> 1;
        float v = ((n & 1) == 0 ? B_re[h * DM + k] : B_im[h * DM + k]) * gam[h];
        WaT[idx] = __float2bfloat16(v);
    } else {
        int j = idx - 512 * 256;
        int d = j >> 9, k = j & 511;
        int h = k >> 1;
        float v = ((k & 1) == 0) ? C_re[d * NH + h] : -C_im[d * NH + h];
        WcT[j] = __float2bfloat16(v);
    }
}

// ---------------------------------------------------------------------------
// MFMA bf16 GEMM:  C[m][n] = sum_k A[m][k] * BT[n][k]   (+ skip: D[n]*X[m][n])
// 128x128 tile, BK=32, 256 threads = 4 waves in 2x2, each wave 64x64 via
// 4x4 grid of 16x16x32 MFMAs. LDS row stride padded to 40 elems (80B) to
// spread banks while keeping 16B alignment for ds_read_b128/ds_write_b128.
// TA=float: convert-on-stage (fuses the x->bf16 cast). TA=bf16: direct.
// ---------------------------------------------------------------------------
#define BM 128
#define BN 128
#define BK 32
#define LDK 40

template <typename TA, typename TC, bool SKIP>
__global__ __launch_bounds__(256) void mfma_gemm(
    const TA* __restrict__ A,    // (M,K) row-major
    const bf16* __restrict__ BT, // (N,K) row-major
    TC* __restrict__ C,          // (M,N) row-major
    int M, int K, int N,
    const float* __restrict__ skip_x,  // (M,N) when SKIP
    const float* __restrict__ Dvec)    // (N,)  when SKIP
{
    __shared__ bf16 sA[BM * LDK];
    __shared__ bf16 sB[BN * LDK];

    const int tid  = threadIdx.x;
    const int lane = tid & 63;
    const int wid  = tid >> 6;
    const int m0 = blockIdx.y * BM;
    const int n0 = blockIdx.x * BN;
    const int tm = (wid >> 1) * 64;   // wave row offset in tile
    const int tn = (wid & 1) * 64;    // wave col offset in tile
    const int l15 = lane & 15;
    const int q   = lane >> 4;

    const int srow = tid >> 2;          // staging row (0..63), +64 on pass 1
    const int scol = (tid & 3) * 8;     // staging col (elements)

    f32x4 zero4 = {0.f, 0.f, 0.f, 0.f};
    f32x4 acc[4][4];
    #pragma unroll
    for (int i = 0; i < 4; ++i)
        #pragma unroll
        for (int j = 0; j < 4; ++j) acc[i][j] = zero4;

    for (int k0 = 0; k0 < K; k0 += BK) {
        #pragma unroll
        for (int p = 0; p < 2; ++p) {
            int r = srow + p * 64;
            // A slab row r, 8 elements at k0+scol
            bf16 tmp[8];
            if constexpr (sizeof(TA) == 4) {
                const float* gp = (const float*)A + (size_t)(m0 + r) * K + k0 + scol;
                float4 v0 = *(const float4*)gp;
                float4 v1 = *(const float4*)(gp + 4);
                tmp[0] = __float2bfloat16(v0.x); tmp[1] = __float2bfloat16(v0.y);
                tmp[2] = __float2bfloat16(v0.z); tmp[3] = __float2bfloat16(v0.w);
                tmp[4] = __float2bfloat16(v1.x); tmp[5] = __float2bfloat16(v1.y);
                tmp[6] = __float2bfloat16(v1.z); tmp[7] = __float2bfloat16(v1.w);
            } else {
                *(int4*)tmp = *(const int4*)((const bf16*)A + (size_t)(m0 + r) * K + k0 + scol);
            }
            *(int4*)&sA[r * LDK + scol] = *(int4*)tmp;
            // B slab row r
            *(int4*)&sB[r * LDK + scol] =
                *(const int4*)(BT + (size_t)(n0 + r) * K + k0 + scol);
        }
        __syncthreads();

        bf16x8 af[4], bfr[4];
        #pragma unroll
        for (int i = 0; i < 4; ++i) {
            af[i]  = *(const bf16x8*)&sA[(tm + i * 16 + l15) * LDK + q * 8];
            bfr[i] = *(const bf16x8*)&sB[(tn + i * 16 + l15) * LDK + q * 8];
        }
        #pragma unroll
        for (int i = 0; i < 4; ++i)
            #pragma unroll
            for (int j = 0; j < 4; ++j)
                acc[i][j] = __builtin_amdgcn_mfma_f32_16x16x32_bf16(
                    af[i], bfr[j], acc[i][j], 0, 0, 0);
        __syncthreads();
    }

    // Epilogue: C/D layout col=lane&15, row=q*4+reg (m89/m91-verified)
    #pragma unroll
    for (int i = 0; i < 4; ++i) {
        #pragma unroll
        for (int j = 0; j < 4; ++j) {
            #pragma unroll
            for (int r = 0; r < 4; ++r) {
                int row = m0 + tm + i * 16 + q * 4 + r;
                int col = n0 + tn + j * 16 + l15;
                float v = acc[i][j][r];
                if constexpr (SKIP) {
                    v += Dvec[col] * skip_x[(size_t)row * N + col];
                }
                if constexpr (sizeof(TC) == 4) {
                    ((float*)C)[(size_t)row * N + col] = v;
                } else {
                    ((bf16*)C)[(size_t)row * N + col] = __float2bfloat16(v);
                }
            }
        }
    }
}

// ---------------------------------------------------------------------------
// Chunked scan, interleaved complex layout: Bu/H row m = t*BATCH+b,
// col 2h = re, 2h+1 = im  -> one dword load + one dword store per (t,h).
// SCHUNK=64, KHALO=32: |Lam|^32 <= 1.3e-14, exact at f32. 1024 blocks.
// ---------------------------------------------------------------------------
#define SCHUNK 64
#define KHALO  32

__global__ __launch_bounds__(256) void scan_kernel(
    const bf16* __restrict__ Bu, const float* __restrict__ lam,
    const int* __restrict__ starts,
    const float* __restrict__ state_re, const float* __restrict__ state_im,
    bf16* __restrict__ H)
{
    int h = threadIdx.x;
    int b = blockIdx.x & (BATCH - 1);
    int c = blockIdx.x / BATCH;

    float lr = lam[h];
    float li = lam[NH + h];

    int t0 = c * SCHUNK;
    int tstart;
    float hre, him;
    if (c == 0) {
        tstart = 0;
        hre = state_re[b * NH + h];
        him = state_im[b * NH + h];
    } else {
        tstart = t0 - KHALO;
        hre = 0.0f; him = 0.0f;
    }
    int tend = t0 + SCHUNK;

    for (int t = tstart; t < tend; ++t) {
        size_t m = (size_t)t * BATCH + b;
        unsigned int v = *(const unsigned int*)(Bu + m * 512 + 2 * h);
        float br = __uint_as_float(v << 16);
        float bi = __uint_as_float(v & 0xffff0000u);
        bool st = (starts[t * BATCH + b] != 0);
        float nr = st ? br : fmaf(lr, hre, fmaf(-li, him, br));
        float ni = st ? bi : fmaf(lr, him, fmaf(li, hre, bi));
        hre = nr; him = ni;
        if (t >= t0) {
            unsigned int packed =
                ((unsigned int)f2bf_bits(him) << 16) | f2bf_bits(hre);
            *(unsigned int*)(H + m * 512 + 2 * h) = packed;
        }
    }
}

// ---------------------------------------------------------------------------
// Launch. Inputs: x, starts, state_re, state_im, nu_log, theta_log,
// B_re, B_im, C_re, C_im, D  (all f32 except starts -> const int*).
// Workspace: lam/gam 4KB | WaT 256KB | WcT 256KB | Bu 64MB | H 64MB (~130MB).
// ---------------------------------------------------------------------------
extern "C" void kernel_launch(void* const* d_in, const int* in_sizes, int n_in,
                              void* d_out, int out_size, void* d_ws, size_t ws_size,
                              hipStream_t stream)
{
    const float* x         = (const float*)d_in[0];
    const int*   starts    = (const int*)d_in[1];
    const float* state_re  = (const float*)d_in[2];
    const float* state_im  = (const float*)d_in[3];
    const float* nu_log    = (const float*)d_in[4];
    const float* theta_log = (const float*)d_in[5];
    const float* B_re      = (const float*)d_in[6];
    const float* B_im      = (const float*)d_in[7];
    const float* C_re      = (const float*)d_in[8];
    const float* C_im      = (const float*)d_in[9];
    const float* Dvec      = (const float*)d_in[10];
    float* out = (float*)d_out;

    char* ws = (char*)d_ws;
    float* lam = (float*)ws;                                   // 2*NH f32
    float* gam = (float*)(ws + 2 * NH * sizeof(float));
    bf16*  WaT = (bf16*)(ws + 4096);                           // 512x256 bf16
    bf16*  WcT = (bf16*)(ws + 4096 + 512 * 256 * 2);           // 256x512 bf16
    bf16*  Bu  = (bf16*)(ws + (1 << 20));                      // 65536x512 bf16 (64MB)
    bf16*  H   = (bf16*)(ws + (1 << 20) + (size_t)M_TOT * 512 * 2); // 64MB

    prep_lam_kernel<<<1, 256, 0, stream>>>(nu_log, theta_log, lam, gam);
    prep_w_kernel<<<1024, 256, 0, stream>>>(B_re, B_im, C_re, C_im, gam, WaT, WcT);

    // Stage A: Bu = x @ WaT^T   (M=65536, K=256, N=512), f32 A converted on stage
    mfma_gemm<float, bf16, false>
        <<<dim3(512 / BN, M_TOT / BM), 256, 0, stream>>>(
        x, WaT, Bu, M_TOT, DM, 512, nullptr, nullptr);

    // Scan: chunked, halo=32
    scan_kernel<<<(T_LEN / SCHUNK) * BATCH, 256, 0, stream>>>(
        Bu, lam, starts, state_re, state_im, H);

    // Stage C: out = H @ WcT^T + D*x   (M=65536, K=512, N=256)
    mfma_gemm<bf16, float, true>
        <<<dim3(DM / BN, M_TOT / BM), 256, 0, stream>>>(
        H, WcT, out, M_TOT, 512, DM, x, Dvec);
}

// Round 4
// 259.980 us; speedup vs baseline: 3.1168x; 1.0138x over previous
//
#include <hip/hip_runtime.h>
#include <hip/hip_bf16.h>

// Problem constants (T, B, H, D_MODEL) = (4096, 16, 256, 256)
#define T_LEN 4096
#define BATCH 16
#define NH    256
#define DM    256
#define M_TOT (T_LEN * BATCH)   // 65536 rows for both GEMMs

typedef __hip_bfloat16 bf16;
typedef __attribute__((ext_vector_type(8))) short bf16x8;  // 8 bf16 = 4 VGPRs
typedef __attribute__((ext_vector_type(4))) float f32x4;

// manual RTNE f32->bf16 (bit-level)
__device__ __forceinline__ unsigned short f2bf_bits(float f) {
    unsigned int u = __float_as_uint(f);
    return (unsigned short)((u + 0x7fffu + ((u >> 16) & 1u)) >> 16);
}

// async global->LDS, 16 B per lane. LDS dest must be wave-uniform base;
// HW scatters lane i to base + i*16 (m97/m104 contract).
typedef const unsigned int __attribute__((address_space(1)))* gas_ptr;
typedef unsigned int __attribute__((address_space(3)))* las_ptr;
__device__ __forceinline__ void async16(const bf16* g, bf16* l) {
    __builtin_amdgcn_global_load_lds((gas_ptr)g, (las_ptr)l, 16, 0, 0);
}

// ---------------------------------------------------------------------------
// Prep 1: Lambda (complex decay) and gamma per head.
// ---------------------------------------------------------------------------
__global__ __launch_bounds__(256) void prep_lam_kernel(
    const float* __restrict__ nu_log, const float* __restrict__ theta_log,
    float* __restrict__ lam /* [2*NH]: re then im */, float* __restrict__ gam)
{
    int h = threadIdx.x;
    float nu  = nu_log[h];
    float th  = theta_log[h];
    float mod = expf(-expf(nu));          // |Lam| <= exp(-1) = 0.368
    float ang = expf(th);
    lam[h]      = mod * cosf(ang);
    lam[NH + h] = mod * sinf(ang);
    gam[h] = sqrtf(fmaxf(1.0f - mod * mod, 1e-8f));
}

// ---------------------------------------------------------------------------
// Prep 2: packed transposed weights (bf16), complex-interleaved layout.
// WaT: (512 x 256) [n][k].  n=2h: B_re[h][k]*gam[h]; n=2h+1: B_im[h][k]*gam[h]
// WcT: (256 x 512) [d][k].  k=2h: C_re[d][h];        k=2h+1: -C_im[d][h]
// ---------------------------------------------------------------------------
__global__ __launch_bounds__(256) void prep_w_kernel(
    const float* __restrict__ B_re, const float* __restrict__ B_im,
    const float* __restrict__ C_re, const float* __restrict__ C_im,
    const float* __restrict__ gam,
    bf16* __restrict__ WaT, bf16* __restrict__ WcT)
{
    int idx = blockIdx.x * 256 + threadIdx.x;   // covers 2 * 131072
    if (idx < 512 * 256) {
        int n = idx >> 8, k = idx & 255;
        int h = n >> 1;
        float v = ((n & 1) == 0 ? B_re[h * DM + k] : B_im[h * DM + k]) * gam[h];
        WaT[idx] = __float2bfloat16(v);
    } else {
        int j = idx - 512 * 256;
        int d = j >> 9, k = j & 511;
        int h = k >> 1;
        float v = ((k & 1) == 0) ? C_re[d * NH + h] : -C_im[d * NH + h];
        WcT[j] = __float2bfloat16(v);
    }
}

// ---------------------------------------------------------------------------
// Convert x (f32) -> xb (bf16), vectorized x8. xb lives in d_out's first
// half (dead until stage C, whose only consumer of xb -- stage A -- is done).
// ---------------------------------------------------------------------------
__global__ __launch_bounds__(256) void cvt_kernel(
    const float* __restrict__ x, bf16* __restrict__ xb)
{
    size_t i = ((size_t)blockIdx.x * 256 + threadIdx.x) * 8;
    float4 a = *(const float4*)(x + i);
    float4 b = *(const float4*)(x + i + 4);
    union { bf16 h[8]; int4 v; } u;
    u.h[0] = __float2bfloat16(a.x); u.h[1] = __float2bfloat16(a.y);
    u.h[2] = __float2bfloat16(a.z); u.h[3] = __float2bfloat16(a.w);
    u.h[4] = __float2bfloat16(b.x); u.h[5] = __float2bfloat16(b.y);
    u.h[6] = __float2bfloat16(b.z); u.h[7] = __float2bfloat16(b.w);
    *(int4*)(xb + i) = u.v;
}

// ---------------------------------------------------------------------------
// MFMA bf16 GEMM (m97 structure): C[m][n] = sum_k A[m][k]*BT[n][k] (+skip)
// 128x128 tile, BK=32, async global_load_lds staging (16B/lane), unpadded
// row-major LDS (contract requirement). 4 waves 2x2, each 64x64 via 4x4
// MFMA 16x16x32. XCD swizzle: all n-blocks of an m-tile on one XCD.
// ---------------------------------------------------------------------------
#define BKE 32   // K elements per slab (64 B per row)

template <typename TC, bool SKIP>
__global__ __launch_bounds__(256) void mfma_gemm(
    const bf16* __restrict__ A,    // (M,K) row-major bf16
    const bf16* __restrict__ BT,   // (N,K) row-major bf16
    TC* __restrict__ C,            // (M,N) row-major
    int K, int N,
    int mpx,                        // m-tiles per XCD (MT/8)
    int lnb,                        // log2(n-tiles)
    const float* __restrict__ skip_x,  // (M,N) f32 when SKIP
    const float* __restrict__ Dvec)    // (N,)  f32 when SKIP
{
    __shared__ bf16 sA[128 * BKE];   // 8 KB
    __shared__ bf16 sB[128 * BKE];   // 8 KB

    const int tid  = threadIdx.x;
    const int lane = tid & 63;
    const int wid  = tid >> 6;

    // XCD-aware swizzle
    const int bid = blockIdx.x;
    const int xcd = bid & 7;
    const int sl  = bid >> 3;
    const int nt  = sl & ((1 << lnb) - 1);
    const int mt  = xcd * mpx + (sl >> lnb);
    const int m0  = mt * 128;
    const int n0  = nt * 128;

    const int tm  = (wid >> 1) * 64;
    const int tn  = (wid & 1) * 64;
    const int l15 = lane & 15;
    const int q   = lane >> 4;

    // staging addresses: wave wid covers rows [wid*32, wid*32+32) in 2 issues
    const bf16* gA = A  + (size_t)(m0 + wid * 32 + (lane >> 2)) * K + (lane & 3) * 8;
    const bf16* gB = BT + (size_t)(n0 + wid * 32 + (lane >> 2)) * K + (lane & 3) * 8;
    const size_t rstep = (size_t)16 * K;     // +16 rows
    bf16* lA = sA + wid * 32 * BKE;          // wave-uniform LDS base
    bf16* lB = sB + wid * 32 * BKE;

    f32x4 acc[4][4];
    #pragma unroll
    for (int i = 0; i < 4; ++i)
        #pragma unroll
        for (int j = 0; j < 4; ++j) acc[i][j] = (f32x4){0.f, 0.f, 0.f, 0.f};

    for (int k0 = 0; k0 < K; k0 += BKE) {
        async16(gA,         lA);
        async16(gA + rstep, lA + 16 * BKE);
        async16(gB,         lB);
        async16(gB + rstep, lB + 16 * BKE);
        gA += BKE; gB += BKE;
        __syncthreads();   // drains vmcnt -> staging complete

        bf16x8 af[4], bfr[4];
        #pragma unroll
        for (int i = 0; i < 4; ++i) {
            af[i]  = *(const bf16x8*)&sA[(tm + i * 16 + l15) * BKE + q * 8];
            bfr[i] = *(const bf16x8*)&sB[(tn + i * 16 + l15) * BKE + q * 8];
        }
        #pragma unroll
        for (int i = 0; i < 4; ++i)
            #pragma unroll
            for (int j = 0; j < 4; ++j)
                acc[i][j] = __builtin_amdgcn_mfma_f32_16x16x32_bf16(
                    af[i], bfr[j], acc[i][j], 0, 0, 0);
        __syncthreads();
    }

    // Epilogue: C/D layout col=lane&15, row=q*4+reg (m89/m91-verified)
    #pragma unroll
    for (int j = 0; j < 4; ++j) {
        int col = n0 + tn + j * 16 + l15;
        float dv = SKIP ? Dvec[col] : 0.0f;
        #pragma unroll
        for (int i = 0; i < 4; ++i) {
            #pragma unroll
            for (int r = 0; r < 4; ++r) {
                int row = m0 + tm + i * 16 + q * 4 + r;
                float v = acc[i][j][r];
                if constexpr (SKIP) {
                    v += dv * skip_x[(size_t)row * N + col];
                }
                if constexpr (sizeof(TC) == 4) {
                    ((float*)C)[(size_t)row * N + col] = v;
                } else {
                    ((bf16*)C)[(size_t)row * N + col] = __float2bfloat16(v);
                }
            }
        }
    }
}

// ---------------------------------------------------------------------------
// Chunked scan, interleaved complex layout (col 2h=re, 2h+1=im).
// SCHUNK=64, KHALO=32 (|Lam|^32 <= 1.3e-14, exact at f32). 1024 blocks.
// One-deep software pipeline on the Bu/starts loads (they don't depend on
// the recurrence state).
// ---------------------------------------------------------------------------
#define SCHUNK 64
#define KHALO  32

__global__ __launch_bounds__(256) void scan_kernel(
    const bf16* __restrict__ Bu, const float* __restrict__ lam,
    const int* __restrict__ starts,
    const float* __restrict__ state_re, const float* __restrict__ state_im,
    bf16* __restrict__ H)
{
    int h = threadIdx.x;
    int b = blockIdx.x & (BATCH - 1);
    int c = blockIdx.x / BATCH;

    float lr = lam[h];
    float li = lam[NH + h];

    int t0 = c * SCHUNK;
    int tstart;
    float hre, him;
    if (c == 0) {
        tstart = 0;
        hre = state_re[b * NH + h];
        him = state_im[b * NH + h];
    } else {
        tstart = t0 - KHALO;
        hre = 0.0f; him = 0.0f;
    }
    int tend = t0 + SCHUNK;

    unsigned int v = *(const unsigned int*)(Bu + ((size_t)tstart * BATCH + b) * 512 + 2 * h);
    int st = starts[tstart * BATCH + b];

    for (int t = tstart; t < tend; ++t) {
        unsigned int vn = 0; int stn = 0;
        if (t + 1 < tend) {
            vn  = *(const unsigned int*)(Bu + ((size_t)(t + 1) * BATCH + b) * 512 + 2 * h);
            stn = starts[(t + 1) * BATCH + b];
        }
        float br = __uint_as_float(v << 16);
        float bi = __uint_as_float(v & 0xffff0000u);
        float nr = st ? br : fmaf(lr, hre, fmaf(-li, him, br));
        float ni = st ? bi : fmaf(lr, him, fmaf(li, hre, bi));
        hre = nr; him = ni;
        if (t >= t0) {
            size_t m = (size_t)t * BATCH + b;
            unsigned int packed =
                ((unsigned int)f2bf_bits(him) << 16) | f2bf_bits(hre);
            *(unsigned int*)(H + m * 512 + 2 * h) = packed;
        }
        v = vn; st = stn;
    }
}

// ---------------------------------------------------------------------------
// Launch. Inputs: x, starts, state_re, state_im, nu_log, theta_log,
// B_re, B_im, C_re, C_im, D  (f32 except starts -> const int*). Output f32.
// xb (bf16 copy of x, 32 MB) parks in d_out's first half: its only consumer
// is stage A, which completes (stream order) before stage C writes d_out.
// Workspace: lam/gam 4KB | WaT 256KB | WcT 256KB | Bu 64MB | H 64MB (~129MB).
// ---------------------------------------------------------------------------
extern "C" void kernel_launch(void* const* d_in, const int* in_sizes, int n_in,
                              void* d_out, int out_size, void* d_ws, size_t ws_size,
                              hipStream_t stream)
{
    const float* x         = (const float*)d_in[0];
    const int*   starts    = (const int*)d_in[1];
    const float* state_re  = (const float*)d_in[2];
    const float* state_im  = (const float*)d_in[3];
    const float* nu_log    = (const float*)d_in[4];
    const float* theta_log = (const float*)d_in[5];
    const float* B_re      = (const float*)d_in[6];
    const float* B_im      = (const float*)d_in[7];
    const float* C_re      = (const float*)d_in[8];
    const float* C_im      = (const float*)d_in[9];
    const float* Dvec      = (const float*)d_in[10];
    float* out = (float*)d_out;

    char* ws = (char*)d_ws;
    float* lam = (float*)ws;                                   // 2*NH f32
    float* gam = (float*)(ws + 2 * NH * sizeof(float));
    bf16*  WaT = (bf16*)(ws + 4096);                           // 512x256 bf16
    bf16*  WcT = (bf16*)(ws + 4096 + 512 * 256 * 2);           // 256x512 bf16
    bf16*  Bu  = (bf16*)(ws + (1 << 20));                      // 65536x512 bf16 (64MB)
    bf16*  H   = (bf16*)(ws + (1 << 20) + (size_t)M_TOT * 512 * 2); // 64MB
    bf16*  xb  = (bf16*)d_out;                                 // 32MB, dead by stage C

    prep_lam_kernel<<<1, 256, 0, stream>>>(nu_log, theta_log, lam, gam);
    prep_w_kernel<<<1024, 256, 0, stream>>>(B_re, B_im, C_re, C_im, gam, WaT, WcT);
    cvt_kernel<<<M_TOT * DM / (256 * 8), 256, 0, stream>>>(x, xb);

    // Stage A: Bu = xb @ WaT^T   (M=65536, K=256, N=512). 2048 blocks.
    mfma_gemm<bf16, false><<<2048, 256, 0, stream>>>(
        xb, WaT, Bu, DM, 512, 64, 2, nullptr, nullptr);

    // Scan: chunked, halo=32. 1024 blocks.
    scan_kernel<<<(T_LEN / SCHUNK) * BATCH, 256, 0, stream>>>(
        Bu, lam, starts, state_re, state_im, H);

    // Stage C: out = H @ WcT^T + D*x   (M=65536, K=512, N=256). 1024 blocks.
    mfma_gemm<float, true><<<1024, 256, 0, stream>>>(
        H, WcT, out, 512, DM, 64, 1, x, Dvec);
}

// Round 5
// 242.520 us; speedup vs baseline: 3.3412x; 1.0720x over previous
//
#include <hip/hip_runtime.h>
#include <hip/hip_bf16.h>

// Problem constants (T, B, H, D_MODEL) = (4096, 16, 256, 256)
#define T_LEN 4096
#define BATCH 16
#define NH    256
#define DM    256
#define M_TOT (T_LEN * BATCH)   // 65536 rows for both GEMMs

typedef __hip_bfloat16 bf16;
typedef __attribute__((ext_vector_type(8))) short bf16x8;  // 8 bf16 = 4 VGPRs
typedef __attribute__((ext_vector_type(4))) float f32x4;

// manual RTNE f32->bf16 (bit-level)
__device__ __forceinline__ unsigned short f2bf_bits(float f) {
    unsigned int u = __float_as_uint(f);
    return (unsigned short)((u + 0x7fffu + ((u >> 16) & 1u)) >> 16);
}

// async global->LDS, 16 B per lane. LDS dest must be wave-uniform base;
// HW scatters lane i to base + i*16 (m97/m104 contract -> no LDS padding).
typedef const unsigned int __attribute__((address_space(1)))* gas_ptr;
typedef unsigned int __attribute__((address_space(3)))* las_ptr;
__device__ __forceinline__ void async16(const bf16* g, bf16* l) {
    __builtin_amdgcn_global_load_lds((gas_ptr)g, (las_ptr)l, 16, 0, 0);
}

// ---------------------------------------------------------------------------
// Prep lam: Lam = exp(-exp(nu_log) + i*exp(theta_log)), [2*NH]: re then im.
// ---------------------------------------------------------------------------
__global__ __launch_bounds__(256) void prep_lam_kernel(
    const float* __restrict__ nu_log, const float* __restrict__ theta_log,
    float* __restrict__ lam)
{
    int h = threadIdx.x;
    float mod = expf(-expf(nu_log[h]));   // |Lam| in [e^-e, e^-1]
    float ang = expf(theta_log[h]);
    lam[h]      = mod * cosf(ang);
    lam[NH + h] = mod * sinf(ang);
}

// ---------------------------------------------------------------------------
// Prep weights (bf16, transposed, complex-interleaved). gamma inlined so this
// has no dependency on prep_lam.
// WaT: (512 x 256) [n][k].  n=2h: B_re[h][k]*gam[h]; n=2h+1: B_im[h][k]*gam[h]
// WcT: (256 x 512) [d][k].  k=2h: C_re[d][h];        k=2h+1: -C_im[d][h]
// ---------------------------------------------------------------------------
__global__ __launch_bounds__(256) void prep_w_kernel(
    const float* __restrict__ nu_log,
    const float* __restrict__ B_re, const float* __restrict__ B_im,
    const float* __restrict__ C_re, const float* __restrict__ C_im,
    bf16* __restrict__ WaT, bf16* __restrict__ WcT)
{
    int idx = blockIdx.x * 256 + threadIdx.x;   // covers 2 * 131072
    if (idx < 512 * 256) {
        int n = idx >> 8, k = idx & 255;
        int h = n >> 1;
        float mod = expf(-expf(nu_log[h]));
        float gam = sqrtf(fmaxf(1.0f - mod * mod, 1e-8f));
        float v = ((n & 1) == 0 ? B_re[h * DM + k] : B_im[h * DM + k]) * gam;
        WaT[idx] = __float2bfloat16(v);
    } else {
        int j = idx - 512 * 256;
        int d = j >> 9, k = j & 511;
        int h = k >> 1;
        float v = ((k & 1) == 0) ? C_re[d * NH + h] : -C_im[d * NH + h];
        WcT[j] = __float2bfloat16(v);
    }
}

// ---------------------------------------------------------------------------
// Convert x (f32) -> xb (bf16), x8 vectorized. xb parks in d_out's first half
// (its only consumer, stage A, completes before the fused kernel writes out).
// ---------------------------------------------------------------------------
__global__ __launch_bounds__(256) void cvt_kernel(
    const float* __restrict__ x, bf16* __restrict__ xb)
{
    size_t i = ((size_t)blockIdx.x * 256 + threadIdx.x) * 8;
    float4 a = *(const float4*)(x + i);
    float4 b = *(const float4*)(x + i + 4);
    union { bf16 h[8]; int4 v; } u;
    u.h[0] = __float2bfloat16(a.x); u.h[1] = __float2bfloat16(a.y);
    u.h[2] = __float2bfloat16(a.z); u.h[3] = __float2bfloat16(a.w);
    u.h[4] = __float2bfloat16(b.x); u.h[5] = __float2bfloat16(b.y);
    u.h[6] = __float2bfloat16(b.z); u.h[7] = __float2bfloat16(b.w);
    *(int4*)(xb + i) = u.v;
}

// ---------------------------------------------------------------------------
// Stage A GEMM (m97 structure): Bu[m][n] = sum_k xb[m][k]*WaT[n][k]
// 128x128 tile, BK=32, async16 staging, 4 waves 2x2, 4x4 MFMA 16x16x32.
// XCD swizzle: the 4 n-tiles of one m-tile land on one XCD (A reuse in L2).
// ---------------------------------------------------------------------------
__global__ __launch_bounds__(256) void gemm_a_kernel(
    const bf16* __restrict__ A,    // xb (M,256)
    const bf16* __restrict__ BT,   // WaT (512,256)
    bf16* __restrict__ Cb)         // Bu (M,512)
{
    __shared__ bf16 sA[128 * 32];   // 8 KB
    __shared__ bf16 sB[128 * 32];   // 8 KB

    const int tid  = threadIdx.x;
    const int lane = tid & 63;
    const int wid  = tid >> 6;

    const int bid = blockIdx.x;          // 2048 blocks
    const int xcd = bid & 7;
    const int sl  = bid >> 3;
    const int nt  = sl & 3;              // 4 n-tiles
    const int mt  = xcd * 64 + (sl >> 2);
    const int m0  = mt * 128;
    const int n0  = nt * 128;

    const int tm  = (wid >> 1) * 64;
    const int tn  = (wid & 1) * 64;
    const int l15 = lane & 15;
    const int q   = lane >> 4;

    const bf16* gA = A  + (size_t)(m0 + wid * 32 + (lane >> 2)) * 256 + (lane & 3) * 8;
    const bf16* gB = BT + (size_t)(n0 + wid * 32 + (lane >> 2)) * 256 + (lane & 3) * 8;
    const size_t rstep = (size_t)16 * 256;
    bf16* lA = sA + wid * 32 * 32;
    bf16* lB = sB + wid * 32 * 32;

    f32x4 acc[4][4];
    #pragma unroll
    for (int i = 0; i < 4; ++i)
        #pragma unroll
        for (int j = 0; j < 4; ++j) acc[i][j] = (f32x4){0.f, 0.f, 0.f, 0.f};

    for (int k0 = 0; k0 < 256; k0 += 32) {
        async16(gA,         lA);
        async16(gA + rstep, lA + 16 * 32);
        async16(gB,         lB);
        async16(gB + rstep, lB + 16 * 32);
        gA += 32; gB += 32;
        __syncthreads();

        bf16x8 af[4], bfr[4];
        #pragma unroll
        for (int i = 0; i < 4; ++i) {
            af[i]  = *(const bf16x8*)&sA[(tm + i * 16 + l15) * 32 + q * 8];
            bfr[i] = *(const bf16x8*)&sB[(tn + i * 16 + l15) * 32 + q * 8];
        }
        #pragma unroll
        for (int i = 0; i < 4; ++i)
            #pragma unroll
            for (int j = 0; j < 4; ++j)
                acc[i][j] = __builtin_amdgcn_mfma_f32_16x16x32_bf16(
                    af[i], bfr[j], acc[i][j], 0, 0, 0);
        __syncthreads();
    }

    // C/D layout: col=lane&15, row=q*4+reg (m89/m91-verified)
    #pragma unroll
    for (int j = 0; j < 4; ++j) {
        int col = n0 + tn + j * 16 + l15;
        #pragma unroll
        for (int i = 0; i < 4; ++i) {
            #pragma unroll
            for (int r = 0; r < 4; ++r) {
                int row = m0 + tm + i * 16 + q * 4 + r;
                Cb[(size_t)row * 512 + col] = __float2bfloat16(acc[i][j][r]);
            }
        }
    }
}

// ---------------------------------------------------------------------------
// Fused scan + stage C. Block = (b, 32-t chunk), 2048 blocks, 256 threads.
// Phase 1: scan Bu rows [t0-16, t0+32) (halo 16: |Lam|^16 <= 1.2e-7, exact
//   vs bf16 rounding) with 8-deep register prefetch; starts cached in LDS;
//   h written to LDS sH (stride 520 elems: 2-way bank aliasing = free).
// Phase 2: out[t0..t0+32)x256 = sH @ WcT^T + D*x, K=512, MFMA from LDS A.
// LDS: sH 33.3KB + sB 16.4KB + starts ~0.2KB = 49.9KB -> 3 blocks/CU.
// ---------------------------------------------------------------------------
#define SC  32
#define HL  16
#define LDH 520   // sH row stride in elems (1040 B, 16B-aligned)
#define PF  8     // scan prefetch depth

__global__ __launch_bounds__(256) void scan_gemmc_kernel(
    const bf16* __restrict__ Bu,     // (M,512)
    const bf16* __restrict__ WcT,    // (256,512)
    const float* __restrict__ lam,   // [2*NH]
    const int* __restrict__ starts,  // (T,B)
    const float* __restrict__ state_re, const float* __restrict__ state_im,
    const float* __restrict__ x,     // (M,256) f32
    const float* __restrict__ Dvec,  // (256,)
    float* __restrict__ out)         // (M,256) f32
{
    __shared__ bf16 sH[SC * LDH];        // 33,280 B
    __shared__ bf16 sB[256 * 32];        // 16,384 B
    __shared__ int  sStarts[SC + HL];

    const int tid = threadIdx.x;
    const int b   = blockIdx.x & (BATCH - 1);
    const int c   = blockIdx.x / BATCH;
    const int t0  = c * SC;
    const int tstart = (c == 0) ? 0 : t0 - HL;
    const int nIter  = t0 + SC - tstart;      // 32 or 48 (both % PF == 0)

    if (tid < nIter) sStarts[tid] = starts[(tstart + tid) * BATCH + b];

    // ---- Phase 1: scan (thread = complex head) ----
    const int h = tid;
    float lr = lam[h], li = lam[NH + h];
    float hre = 0.0f, him = 0.0f;
    if (c == 0) { hre = state_re[b * NH + h]; him = state_im[b * NH + h]; }

    const bf16* bp = Bu + ((size_t)tstart * BATCH + b) * 512 + 2 * h;
    const size_t tstride = (size_t)BATCH * 512;   // elems per t step

    unsigned int vbuf[PF];
    #pragma unroll
    for (int p = 0; p < PF; ++p)
        vbuf[p] = (p < nIter) ? *(const unsigned int*)(bp + p * tstride) : 0u;

    __syncthreads();   // sStarts ready

    const int skip = nIter - SC;   // halo iterations before t0
    for (int base = 0; base < nIter; base += PF) {
        #pragma unroll
        for (int p = 0; p < PF; ++p) {
            int it = base + p;
            unsigned int v = vbuf[p];
            int tp = it + PF;
            if (tp < nIter)
                vbuf[p] = *(const unsigned int*)(bp + (size_t)tp * tstride);
            float br = __uint_as_float(v << 16);
            float bi = __uint_as_float(v & 0xffff0000u);
            int st = sStarts[it];
            float nr = st ? br : fmaf(lr, hre, fmaf(-li, him, br));
            float ni = st ? bi : fmaf(lr, him, fmaf(li, hre, bi));
            hre = nr; him = ni;
            int tl = it - skip;
            if (tl >= 0) {
                unsigned int packed =
                    ((unsigned int)f2bf_bits(him) << 16) | f2bf_bits(hre);
                *(unsigned int*)&sH[tl * LDH + 2 * h] = packed;
            }
        }
    }
    __syncthreads();

    // ---- Phase 2: GEMM 32x256, K=512, A from sH ----
    const int lane = tid & 63;
    const int w    = tid >> 6;          // wave -> 64-col group
    const int l15  = lane & 15;
    const int q    = lane >> 4;

    f32x4 acc[2][4];
    #pragma unroll
    for (int i = 0; i < 2; ++i)
        #pragma unroll
        for (int j = 0; j < 4; ++j) acc[i][j] = (f32x4){0.f, 0.f, 0.f, 0.f};

    const bf16* gB = WcT + (size_t)(w * 64 + (lane >> 2)) * 512 + (lane & 3) * 8;
    bf16* lB = sB + w * 64 * 32;        // wave-uniform LDS base

    for (int k0 = 0; k0 < 512; k0 += 32) {
        async16(gB,              lB);
        async16(gB + 16 * 512,   lB + 16 * 32);
        async16(gB + 32 * 512,   lB + 32 * 32);
        async16(gB + 48 * 512,   lB + 48 * 32);
        gB += 32;
        __syncthreads();

        bf16x8 af[2], bfr[4];
        #pragma unroll
        for (int i = 0; i < 2; ++i)
            af[i] = *(const bf16x8*)&sH[(i * 16 + l15) * LDH + k0 + q * 8];
        #pragma unroll
        for (int j = 0; j < 4; ++j)
            bfr[j] = *(const bf16x8*)&sB[(w * 64 + j * 16 + l15) * 32 + q * 8];
        #pragma unroll
        for (int i = 0; i < 2; ++i)
            #pragma unroll
            for (int j = 0; j < 4; ++j)
                acc[i][j] = __builtin_amdgcn_mfma_f32_16x16x32_bf16(
                    af[i], bfr[j], acc[i][j], 0, 0, 0);
        __syncthreads();
    }

    // Epilogue: out rows m = (t0 + tl)*16 + b, + D*x skip
    #pragma unroll
    for (int j = 0; j < 4; ++j) {
        int col = w * 64 + j * 16 + l15;
        float dv = Dvec[col];
        #pragma unroll
        for (int i = 0; i < 2; ++i) {
            #pragma unroll
            for (int r = 0; r < 4; ++r) {
                int tl = i * 16 + q * 4 + r;
                size_t m = (size_t)(t0 + tl) * BATCH + b;
                out[m * 256 + col] = acc[i][j][r] + dv * x[m * 256 + col];
            }
        }
    }
}

// ---------------------------------------------------------------------------
// Launch. Inputs: x, starts, state_re, state_im, nu_log, theta_log,
// B_re, B_im, C_re, C_im, D (f32 except starts -> const int*). Output f32.
// Workspace: lam 2KB | WaT 256KB | WcT 256KB | Bu 64MB (~65MB total).
// xb (32MB) parks in d_out's first half: consumed only by stage A, which is
// stream-ordered before the fused kernel overwrites d_out.
// ---------------------------------------------------------------------------
extern "C" void kernel_launch(void* const* d_in, const int* in_sizes, int n_in,
                              void* d_out, int out_size, void* d_ws, size_t ws_size,
                              hipStream_t stream)
{
    const float* x         = (const float*)d_in[0];
    const int*   starts    = (const int*)d_in[1];
    const float* state_re  = (const float*)d_in[2];
    const float* state_im  = (const float*)d_in[3];
    const float* nu_log    = (const float*)d_in[4];
    const float* theta_log = (const float*)d_in[5];
    const float* B_re      = (const float*)d_in[6];
    const float* B_im      = (const float*)d_in[7];
    const float* C_re      = (const float*)d_in[8];
    const float* C_im      = (const float*)d_in[9];
    const float* Dvec      = (const float*)d_in[10];
    float* out = (float*)d_out;

    char* ws = (char*)d_ws;
    float* lam = (float*)ws;                            // 2*NH f32
    bf16*  WaT = (bf16*)(ws + 4096);                    // 512x256 bf16
    bf16*  WcT = (bf16*)(ws + 4096 + 512 * 256 * 2);    // 256x512 bf16
    bf16*  Bu  = (bf16*)(ws + (1 << 20));               // 65536x512 bf16 (64MB)
    bf16*  xb  = (bf16*)d_out;                          // 32MB, dead by fused

    prep_lam_kernel<<<1, 256, 0, stream>>>(nu_log, theta_log, lam);
    prep_w_kernel<<<1024, 256, 0, stream>>>(nu_log, B_re, B_im, C_re, C_im, WaT, WcT);
    cvt_kernel<<<M_TOT * DM / (256 * 8), 256, 0, stream>>>(x, xb);

    // Stage A: Bu = xb @ WaT^T   (M=65536, K=256, N=512). 2048 blocks.
    gemm_a_kernel<<<2048, 256, 0, stream>>>(xb, WaT, Bu);

    // Fused scan + stage C: 2048 blocks = (chunk, b).
    scan_gemmc_kernel<<<(T_LEN / SC) * BATCH, 256, 0, stream>>>(
        Bu, WcT, lam, starts, state_re, state_im, x, Dvec, out);
}